// Round 2
// baseline (422.876 us; speedup 1.0000x reference)
//
#include <hip/hip_runtime.h>

// VQ: N=262144 vectors (64x4096), D=64, K=512 codewords, fp32.
// out (float32): quantized[16777216] | indices[262144] (as float) | loss[1]
//
// Structure (R2): one thread per input vector, x held in 64 VGPRs.
// Codewords read with wave-uniform indices -> scalar-pipe s_load (or
// same-address VMEM) -> VALU issue slots are ~pure v_fmac_f32.
// No LDS tiles, no barriers in the main loop.

#define NVEC  262144
#define DDIM  64
#define KCW   512
#define LOSS_SCALE (0.25f / 16777216.0f)   // COMMITMENT_COST / (N*D)

__global__ void csq_zero_kernel(const float* __restrict__ cw,
                                float* __restrict__ csq,
                                float* __restrict__ loss_slot) {
    int n = blockIdx.x * blockDim.x + threadIdx.x;
    if (n < KCW) {
        const float4* r = (const float4*)(cw + n * DDIM);
        float s = 0.f;
        #pragma unroll
        for (int t = 0; t < 16; ++t) {
            float4 v = r[t];
            s += v.x * v.x + v.y * v.y + v.z * v.z + v.w * v.w;
        }
        csq[n] = s;
    }
    if (n == 0) *loss_slot = 0.f;   // d_out poisoned before every launch
}

__global__ __launch_bounds__(256, 3)   // VGPR cap 170; est. usage ~120, no spill
void vq_kernel(const float* __restrict__ x, const float* __restrict__ cw,
               const float* __restrict__ csq,
               float* __restrict__ out_q, float* __restrict__ out_idx,
               float* __restrict__ out_loss) {
    __shared__ float red[4];
    const int tid = threadIdx.x;
    const long row = (long)blockIdx.x * 256 + tid;

    // ---- x row -> 64 VGPRs (lines fully consumed across the 16 loads) ----
    float4 xv[16];
    {
        const float4* xg = (const float4*)(x + row * DDIM);
        #pragma unroll
        for (int t = 0; t < 16; ++t) xv[t] = xg[t];
    }

    // ---- argmin over score(n) = csq[n] - 2*dot(x, c_n)  (xsq is constant) ----
    float bestv = 3.402823466e38f;
    int   besti = 0;
    const float4* cw4 = (const float4*)cw;   // uniform-index reads

    #pragma unroll 2
    for (int n = 0; n < KCW; ++n) {
        float a0 = 0.f, a1 = 0.f, a2 = 0.f, a3 = 0.f;  // 4 chains: hide FMA latency
        #pragma unroll
        for (int t = 0; t < 16; ++t) {
            float4 c = cw4[(n << 4) + t];
            a0 = __builtin_fmaf(xv[t].x, c.x, a0);
            a1 = __builtin_fmaf(xv[t].y, c.y, a1);
            a2 = __builtin_fmaf(xv[t].z, c.z, a2);
            a3 = __builtin_fmaf(xv[t].w, c.w, a3);
        }
        float s = (a0 + a1) + (a2 + a3);
        float score = __builtin_fmaf(-2.f, s, csq[n]);
        if (score < bestv) { bestv = score; besti = n; }   // n ascending => first min
    }

    out_idx[row] = (float)besti;   // harness reads all outputs as float32

    // ---- quantized write + elementwise commitment loss (x still in regs) ----
    float ls = 0.f;
    {
        const float4* qg = (const float4*)(cw + besti * DDIM);  // 128KB table, L2-hot
        float4* og = (float4*)(out_q + row * DDIM);
        #pragma unroll
        for (int t = 0; t < 16; ++t) {
            float4 q = qg[t];
            og[t] = q;
            float dx = q.x - xv[t].x, dy = q.y - xv[t].y;
            float dz = q.z - xv[t].z, dw = q.w - xv[t].w;
            ls += dx * dx + dy * dy + dz * dz + dw * dw;
        }
    }
    #pragma unroll
    for (int off = 32; off > 0; off >>= 1) ls += __shfl_down(ls, off, 64);
    if ((tid & 63) == 0) red[tid >> 6] = ls;
    __syncthreads();
    if (tid == 0)
        atomicAdd(out_loss, ((red[0] + red[1]) + (red[2] + red[3])) * LOSS_SCALE);
}

extern "C" void kernel_launch(void* const* d_in, const int* in_sizes, int n_in,
                              void* d_out, int out_size, void* d_ws, size_t ws_size,
                              hipStream_t stream) {
    const float* x  = (const float*)d_in[0];   // (64,4096,64) fp32
    const float* cw = (const float*)d_in[1];   // (512,64) fp32
    float* out      = (float*)d_out;
    float* out_q    = out;                      // 16777216
    float* out_idx  = out + 16777216;           // 262144
    float* out_loss = out + 16777216 + 262144;  // 1
    float* csq      = (float*)d_ws;             // 512 floats scratch

    csq_zero_kernel<<<8, 64, 0, stream>>>(cw, csq, out_loss);
    vq_kernel<<<NVEC / 256, 256, 0, stream>>>(x, cw, csq, out_q, out_idx, out_loss);
}

// Round 3
// 356.692 us; speedup vs baseline: 1.1855x; 1.1855x over previous
//
#include <hip/hip_runtime.h>

// VQ: N=262144 vectors (64x4096), D=64, K=512 codewords, fp32.
// out (float32): quantized[16777216] | indices[262144] (as float) | loss[1]
//
// R3 structure: 2 input rows per thread held in VGPRs (128 regs).
// Codewords staged per-block into LDS in 32KB chunks; inner loop reads them
// with wave-uniform ds_read_b128 (broadcast, conflict-free, 16B unique data)
// through a 4-sub-chunk register ring prefetching codeword n+1 while
// computing n. No SQC path, no scratch, no VMEM in the main loop.

#define NVEC   262144
#define DDIM   64
#define KCW    512
#define CHUNK  128                       // codewords per LDS chunk (32 KB)
#define NCHUNK (KCW / CHUNK)
#define LOSS_SCALE (0.25f / 16777216.0f) // COMMITMENT_COST / (N*D)

__global__ void csq_zero_kernel(const float* __restrict__ cw,
                                float* __restrict__ csq,
                                float* __restrict__ loss_slot) {
    int n = blockIdx.x * blockDim.x + threadIdx.x;
    if (n < KCW) {
        const float4* r = (const float4*)(cw + n * DDIM);
        float s = 0.f;
        #pragma unroll
        for (int t = 0; t < 16; ++t) {
            float4 v = r[t];
            s += v.x * v.x + v.y * v.y + v.z * v.z + v.w * v.w;
        }
        csq[n] = s;
    }
    if (n == 0) *loss_slot = 0.f;   // d_out poisoned before every launch
}

__global__ __launch_bounds__(256, 2)   // VGPR cap 256; est. ~220, no spill
void vq_kernel(const float* __restrict__ x, const float* __restrict__ cw,
               const float* __restrict__ csq,
               float* __restrict__ out_q, float* __restrict__ out_idx,
               float* __restrict__ out_loss) {
    __shared__ float Bs[CHUNK * DDIM];   // 32 KB codeword chunk
    __shared__ float csqs[KCW];          // 2 KB
    __shared__ float red[4];

    const int tid = threadIdx.x;
    const long r0 = (long)blockIdx.x * 512 + tid;   // rows r0 and r0+256
    const long r1 = r0 + 256;

    // ---- stage both x rows into registers (coalesced float4) ----
    float4 xv0[16], xv1[16];
    {
        const float4* g0 = (const float4*)(x + r0 * DDIM);
        const float4* g1 = (const float4*)(x + r1 * DDIM);
        #pragma unroll
        for (int t = 0; t < 16; ++t) { xv0[t] = g0[t]; xv1[t] = g1[t]; }
    }
    // ---- csq table into LDS once ----
    csqs[tid] = csq[tid];
    csqs[tid + 256] = csq[tid + 256];

    float best0 = 3.402823466e38f, best1 = 3.402823466e38f;
    int   bi0 = 0, bi1 = 0;

    for (int ch = 0; ch < NCHUNK; ++ch) {
        __syncthreads();   // prior chunk fully consumed (also covers csqs store)
        // ---- stage 32 KB chunk: 8 float4 per thread, coalesced ----
        {
            const float4* g = (const float4*)(cw + ch * CHUNK * DDIM);
            float4* b = (float4*)Bs;
            #pragma unroll
            for (int j = 0; j < 8; ++j) b[tid + 256 * j] = g[tid + 256 * j];
        }
        __syncthreads();

        // ---- preload codeword 0 into the register ring ----
        float4 cb[4][4];
        #pragma unroll
        for (int s = 0; s < 4; ++s)
            #pragma unroll
            for (int t = 0; t < 4; ++t)
                cb[s][t] = *(const float4*)&Bs[s * 16 + t * 4];

        for (int n = 0; n < CHUNK; ++n) {
            const int nn = (n + 1) & (CHUNK - 1);   // wrap read harmless (discarded)
            const float* nrow = &Bs[nn * DDIM];
            float a0, a1, a2, a3, b0, b1, b2, b3;
            #pragma unroll
            for (int s = 0; s < 4; ++s) {
                #pragma unroll
                for (int t = 0; t < 4; ++t) {
                    const float4 c  = cb[s][t];
                    const float4 xa = xv0[s * 4 + t];
                    const float4 xb = xv1[s * 4 + t];
                    if (s == 0 && t == 0) {
                        a0 = xa.x * c.x; a1 = xa.y * c.y;
                        a2 = xa.z * c.z; a3 = xa.w * c.w;
                        b0 = xb.x * c.x; b1 = xb.y * c.y;
                        b2 = xb.z * c.z; b3 = xb.w * c.w;
                    } else {
                        a0 = __builtin_fmaf(xa.x, c.x, a0);
                        a1 = __builtin_fmaf(xa.y, c.y, a1);
                        a2 = __builtin_fmaf(xa.z, c.z, a2);
                        a3 = __builtin_fmaf(xa.w, c.w, a3);
                        b0 = __builtin_fmaf(xb.x, c.x, b0);
                        b1 = __builtin_fmaf(xb.y, c.y, b1);
                        b2 = __builtin_fmaf(xb.z, c.z, b2);
                        b3 = __builtin_fmaf(xb.w, c.w, b3);
                    }
                }
                // prefetch codeword n+1, sub-chunk s (issues after the FMAs
                // that read cb[s]; 256-cyc distance to next use)
                #pragma unroll
                for (int t = 0; t < 4; ++t)
                    cb[s][t] = *(const float4*)&nrow[s * 16 + t * 4];
            }
            const float cs = csqs[ch * CHUNK + n];
            const int   gn = ch * CHUNK + n;
            float s0 = (a0 + a1) + (a2 + a3);
            float s1 = (b0 + b1) + (b2 + b3);
            float sc0 = __builtin_fmaf(-2.f, s0, cs);
            float sc1 = __builtin_fmaf(-2.f, s1, cs);
            if (sc0 < best0) { best0 = sc0; bi0 = gn; }   // n ascending => first min
            if (sc1 < best1) { best1 = sc1; bi1 = gn; }
        }
    }

    out_idx[r0] = (float)bi0;
    out_idx[r1] = (float)bi1;

    // ---- quantized write + elementwise commitment loss (x still in regs) ----
    float ls = 0.f;
    {
        const float4* q0 = (const float4*)(cw + bi0 * DDIM);  // 128KB table, L2-hot
        const float4* q1 = (const float4*)(cw + bi1 * DDIM);
        float4* o0 = (float4*)(out_q + r0 * DDIM);
        float4* o1 = (float4*)(out_q + r1 * DDIM);
        #pragma unroll
        for (int t = 0; t < 16; ++t) {
            float4 q = q0[t];
            o0[t] = q;
            float dx = q.x - xv0[t].x, dy = q.y - xv0[t].y;
            float dz = q.z - xv0[t].z, dw = q.w - xv0[t].w;
            ls += dx * dx + dy * dy + dz * dz + dw * dw;
        }
        #pragma unroll
        for (int t = 0; t < 16; ++t) {
            float4 q = q1[t];
            o1[t] = q;
            float dx = q.x - xv1[t].x, dy = q.y - xv1[t].y;
            float dz = q.z - xv1[t].z, dw = q.w - xv1[t].w;
            ls += dx * dx + dy * dy + dz * dz + dw * dw;
        }
    }
    #pragma unroll
    for (int off = 32; off > 0; off >>= 1) ls += __shfl_down(ls, off, 64);
    if ((tid & 63) == 0) red[tid >> 6] = ls;
    __syncthreads();
    if (tid == 0)
        atomicAdd(out_loss, ((red[0] + red[1]) + (red[2] + red[3])) * LOSS_SCALE);
}

extern "C" void kernel_launch(void* const* d_in, const int* in_sizes, int n_in,
                              void* d_out, int out_size, void* d_ws, size_t ws_size,
                              hipStream_t stream) {
    const float* x  = (const float*)d_in[0];   // (64,4096,64) fp32
    const float* cw = (const float*)d_in[1];   // (512,64) fp32
    float* out      = (float*)d_out;
    float* out_q    = out;                      // 16777216
    float* out_idx  = out + 16777216;           // 262144
    float* out_loss = out + 16777216 + 262144;  // 1
    float* csq      = (float*)d_ws;             // 512 floats scratch

    csq_zero_kernel<<<8, 64, 0, stream>>>(cw, csq, out_loss);
    vq_kernel<<<NVEC / 512, 256, 0, stream>>>(x, cw, csq, out_q, out_idx, out_loss);
}

// Round 4
// 325.518 us; speedup vs baseline: 1.2991x; 1.0958x over previous
//
#include <hip/hip_runtime.h>

// VQ: N=262144 vectors (64x4096), D=64, K=512 codewords, fp32.
// out (float32): quantized[16777216] | indices[262144] (as float) | loss[1]
//
// R4: classic two-LDS-tile structure, balanced for the CDNA4 DS pipe.
//  - BM=128 rows staged ONCE per block (K=64 = full depth), TRANSPOSED
//    (At[k][m]) so a-frag reads hit 4 distinct banks (natural layout is
//    4-way conflicted for any 16B-aligned stride).
//  - B chunks of 128 codewords, row stride 68 floats (2-way = free).
//  - Thread tile TM=8 x TN=8: per k-quad 16 ds_read_b128 (128 CU-cyc for
//    4 waves) vs 256 FMA (512 SIMD-cyc) -> DS and VALU balanced.
//  - ~170 VGPR, launch_bounds(256,1): no cap, no spill (R3 lesson).

#define NVEC    262144
#define DDIM    64
#define KCW     512
#define BM      128
#define BN      128
#define NCHUNK  (KCW / BN)
#define BSTRIDE 68
#define LOSS_SCALE (0.25f / 16777216.0f)   // COMMITMENT_COST / (N*D)

__global__ void csq_zero_kernel(const float* __restrict__ cw,
                                float* __restrict__ csq,
                                float* __restrict__ loss_slot) {
    int n = blockIdx.x * blockDim.x + threadIdx.x;
    if (n < KCW) {
        const float4* r = (const float4*)(cw + n * DDIM);
        float s = 0.f;
        #pragma unroll
        for (int t = 0; t < 16; ++t) {
            float4 v = r[t];
            s += v.x * v.x + v.y * v.y + v.z * v.z + v.w * v.w;
        }
        csq[n] = s;
    }
    if (n == 0) *loss_slot = 0.f;   // d_out poisoned before every launch
}

__global__ __launch_bounds__(256, 1)
void vq_kernel(const float* __restrict__ x, const float* __restrict__ cw,
               const float* __restrict__ csq,
               float* __restrict__ out_q, float* __restrict__ out_idx,
               float* __restrict__ out_loss) {
    __shared__ float At[DDIM * BM];        // 32 KB, transposed: At[k*BM+m]
    __shared__ float Bs[BN * BSTRIDE];     // 34 KB, Bs[n*68+k]
    __shared__ float csqs[KCW];            // 2 KB
    __shared__ int   win[BM];
    __shared__ float red[4];

    const int tid = threadIdx.x;
    const int tx  = tid & 15;              // codeword group (TN=8: n = tx+16j)
    const int ty  = tid >> 4;              // row group (TM=8: m = ty*8+i)
    const long base_row = (long)blockIdx.x * BM;

    // ---- stage x tile ONCE, transposed (scalar scatter, conflict-free) ----
    {
        int m = tid >> 1, h = tid & 1;
        const float4* g = (const float4*)(x + (base_row + m) * DDIM + h * 32);
        #pragma unroll
        for (int t = 0; t < 8; ++t) {
            float4 v = g[t];
            int k0 = h * 32 + t * 4;
            At[(k0 + 0) * BM + m] = v.x;
            At[(k0 + 1) * BM + m] = v.y;
            At[(k0 + 2) * BM + m] = v.z;
            At[(k0 + 3) * BM + m] = v.w;
        }
        csqs[tid]       = csq[tid];
        csqs[tid + 256] = csq[tid + 256];
    }

    float best[8]; int bidx[8];
    #pragma unroll
    for (int i = 0; i < 8; ++i) { best[i] = 3.402823466e38f; bidx[i] = 0; }

    for (int ch = 0; ch < NCHUNK; ++ch) {
        __syncthreads();   // prior chunk consumed (first iter: covers At/csqs)
        // ---- stage B chunk: 128 codewords x 64, coalesced, stride 68 ----
        {
            int n = tid >> 1, h = tid & 1;
            const float4* g = (const float4*)(cw + (ch * BN + n) * DDIM + h * 32);
            float* bp = &Bs[n * BSTRIDE + h * 32];
            #pragma unroll
            for (int t = 0; t < 8; ++t) *(float4*)(bp + 4 * t) = g[t];
        }
        __syncthreads();

        float acc[8][8];
        #pragma unroll
        for (int i = 0; i < 8; ++i)
            #pragma unroll
            for (int j = 0; j < 8; ++j) acc[i][j] = 0.f;

        #pragma unroll 4
        for (int t4 = 0; t4 < 16; ++t4) {
            float4 af[4][2];               // af[k][h] = rows ty*8+4h.. at depth t4*4+k
            float4 bf[8];                  // bf[j]    = depths t4*4.. of codeword tx+16j
            #pragma unroll
            for (int k = 0; k < 4; ++k) {
                const float* ap = &At[(t4 * 4 + k) * BM + ty * 8];
                af[k][0] = *(const float4*)ap;
                af[k][1] = *(const float4*)(ap + 4);
            }
            #pragma unroll
            for (int j = 0; j < 8; ++j)
                bf[j] = *(const float4*)&Bs[(tx + 16 * j) * BSTRIDE + t4 * 4];

            const float* afp = (const float*)af;
            #pragma unroll
            for (int j = 0; j < 8; ++j) {
                const float* bp = (const float*)&bf[j];
                #pragma unroll
                for (int k = 0; k < 4; ++k) {
                    float b = bp[k];
                    #pragma unroll
                    for (int h = 0; h < 2; ++h)
                        #pragma unroll
                        for (int r = 0; r < 4; ++r)
                            acc[h * 4 + r][j] =
                                __builtin_fmaf(afp[(k * 2 + h) * 4 + r], b,
                                               acc[h * 4 + r][j]);
                }
            }
        }

        // ---- score + running argmin (j ascending => n ascending per lane) ----
        #pragma unroll
        for (int j = 0; j < 8; ++j) {
            int gn = ch * BN + tx + 16 * j;
            float cs = csqs[gn];
            #pragma unroll
            for (int i = 0; i < 8; ++i) {
                float sc = __builtin_fmaf(-2.f, acc[i][j], cs);
                if (sc < best[i]) { best[i] = sc; bidx[i] = gn; }
            }
        }
    }

    // ---- cross-lane argmin over the 16 tx lanes, per row ----
    #pragma unroll
    for (int i = 0; i < 8; ++i) {
        float d = best[i]; int ix = bidx[i];
        #pragma unroll
        for (int off = 8; off > 0; off >>= 1) {
            float d2 = __shfl_down(d, off, 16);
            int   i2 = __shfl_down(ix, off, 16);
            if (d2 < d || (d2 == d && i2 < ix)) { d = d2; ix = i2; }
        }
        if (tx == 0) {
            int m = ty * 8 + i;
            win[m] = ix;
            out_idx[base_row + m] = (float)ix;
        }
    }
    __syncthreads();

    // ---- quantized write + elementwise commitment loss ----
    float ls = 0.f;
    {
        int m = tid >> 1, h = tid & 1;
        int w = win[m];
        const float4* qg = (const float4*)(cw + w * DDIM + h * 32);  // L2-hot
        float4* og = (float4*)(out_q + (base_row + m) * DDIM + h * 32);
        #pragma unroll
        for (int t = 0; t < 8; ++t) {
            float4 q = qg[t];
            og[t] = q;
            int k0 = h * 32 + t * 4;
            float x0 = At[(k0 + 0) * BM + m], x1 = At[(k0 + 1) * BM + m];
            float x2 = At[(k0 + 2) * BM + m], x3 = At[(k0 + 3) * BM + m];
            float d0 = q.x - x0, d1 = q.y - x1;
            float d2 = q.z - x2, d3 = q.w - x3;
            ls += d0 * d0 + d1 * d1 + d2 * d2 + d3 * d3;
        }
    }
    #pragma unroll
    for (int off = 32; off > 0; off >>= 1) ls += __shfl_down(ls, off, 64);
    if ((tid & 63) == 0) red[tid >> 6] = ls;
    __syncthreads();
    if (tid == 0)
        atomicAdd(out_loss, ((red[0] + red[1]) + (red[2] + red[3])) * LOSS_SCALE);
}

extern "C" void kernel_launch(void* const* d_in, const int* in_sizes, int n_in,
                              void* d_out, int out_size, void* d_ws, size_t ws_size,
                              hipStream_t stream) {
    const float* x  = (const float*)d_in[0];   // (64,4096,64) fp32
    const float* cw = (const float*)d_in[1];   // (512,64) fp32
    float* out      = (float*)d_out;
    float* out_q    = out;                      // 16777216
    float* out_idx  = out + 16777216;           // 262144
    float* out_loss = out + 16777216 + 262144;  // 1
    float* csq      = (float*)d_ws;             // 512 floats scratch

    csq_zero_kernel<<<8, 64, 0, stream>>>(cw, csq, out_loss);
    vq_kernel<<<NVEC / BM, 256, 0, stream>>>(x, cw, csq, out_q, out_idx, out_loss);
}